// Round 2
// baseline (719.205 us; speedup 1.0000x reference)
//
#include <hip/hip_runtime.h>
#include <cstdint>

#define CIN 128
#define NH 8
#define CH 32
#define LDQ 1024   // qkvg row stride (q|k|v|g, 4*256)

// ---------------- prep: detect mask element width ----------------
// jax bool may arrive as uint8 (1B) or int32 (4B). Reads only the first
// 65536 bytes (safe under both layouts). int32 {0,1} little-endian has
// bytes: i%4==0 in {0,1}, i%4!=0 == 0. Random uint8 0/1 violates this
// massively. flag=1 -> int32, flag=0 -> uint8. Deterministic per run.
__global__ __launch_bounds__(256) void detect_mask(
    const unsigned char* __restrict__ m, unsigned int* __restrict__ flag)
{
  __shared__ int viol;
  if (threadIdx.x == 0) viol = 0;
  __syncthreads();
  int v = 0;
  const int base = threadIdx.x * 256;
  for (int j = 0; j < 256; ++j) {
    int i = base + j;
    unsigned char b = m[i];
    v |= ((i & 3) ? (b != 0) : (b > 1)) ? 1 : 0;
  }
  if (v) atomicOr(&viol, 1);
  __syncthreads();
  if (threadIdx.x == 0) *flag = viol ? 0u : 1u;
}

// ---------------- prep: bias transpose [h][q][k] -> [h][k][q] ----------------
__global__ __launch_bounds__(256) void bias_transpose(
    const float* __restrict__ bias, float* __restrict__ biasT)
{
  __shared__ float t[32][33];
  const int h = blockIdx.z;
  const int i0 = blockIdx.x * 32, k0 = blockIdx.y * 32;
  const int cc = threadIdx.x & 31, rr = threadIdx.x >> 5;  // rr 0..7
  const float* src = bias + h * 65536;
  float* dst = biasT + h * 65536;
#pragma unroll
  for (int e = 0; e < 4; ++e) {
    int r = rr + e * 8;
    t[r][cc] = src[(i0 + r) * 256 + k0 + cc];
  }
  __syncthreads();
#pragma unroll
  for (int e = 0; e < 4; ++e) {
    int r = rr + e * 8;
    dst[(k0 + r) * 256 + i0 + cc] = t[cc][r];
  }
}

// ---------------- fused QKVG projection (per chunk of rows) ----------------
// qkvg[pos][0:256)=q/sqrt(C), [256:512)=k, [512:768)=v, [768:1024)=sigmoid(xWg+bg)
// BM=128, BN=64, BK=64, 256 threads, 8x4 microtile. x/qkvg are chunk-local.
__global__ __launch_bounds__(256) void proj_qkvg(
    const float* __restrict__ x,
    const float* __restrict__ Wq, const float* __restrict__ Wk,
    const float* __restrict__ Wv, const float* __restrict__ Wg,
    const float* __restrict__ bg, float* __restrict__ qkvg)
{
  __shared__ float At[64][132];   // [k][r], padded
  __shared__ float Wl[64][68];    // [k][n], padded
  const int tid = threadIdx.x;
  const int tx = tid & 15, ty = tid >> 4;
  const int n0 = blockIdx.x * 64;
  const int row0 = blockIdx.y * 128;
  const int seg = n0 >> 8;                  // 0=q 1=k 2=v 3=g
  const float* W = (seg == 0) ? Wq : (seg == 1) ? Wk : (seg == 2) ? Wv : Wg;
  const int nw = n0 & 255;

  float acc[8][4];
#pragma unroll
  for (int i = 0; i < 8; ++i)
#pragma unroll
    for (int j = 0; j < 4; ++j) acc[i][j] = 0.f;

  for (int k0 = 0; k0 < 128; k0 += 64) {
#pragma unroll
    for (int j = 0; j < 8; ++j) {           // A tile 128r x 64k, store transposed
      int f = tid + j * 256;
      int r = f >> 4, kv = f & 15;
      const float4 a = *(const float4*)(x + (size_t)(row0 + r) * CIN + k0 + kv * 4);
      At[kv * 4 + 0][r] = a.x; At[kv * 4 + 1][r] = a.y;
      At[kv * 4 + 2][r] = a.z; At[kv * 4 + 3][r] = a.w;
    }
#pragma unroll
    for (int j = 0; j < 4; ++j) {           // W tile 64k x 64n
      int f = tid + j * 256;
      int kr = f >> 4, nv = f & 15;
      *(float4*)&Wl[kr][nv * 4] = *(const float4*)(W + (k0 + kr) * 256 + nw + nv * 4);
    }
    __syncthreads();
#pragma unroll 16
    for (int k = 0; k < 64; ++k) {
      float4 a0 = *(const float4*)&At[k][ty * 8];
      float4 a1 = *(const float4*)&At[k][ty * 8 + 4];
      float4 w  = *(const float4*)&Wl[k][tx * 4];
      acc[0][0] += a0.x * w.x; acc[0][1] += a0.x * w.y; acc[0][2] += a0.x * w.z; acc[0][3] += a0.x * w.w;
      acc[1][0] += a0.y * w.x; acc[1][1] += a0.y * w.y; acc[1][2] += a0.y * w.z; acc[1][3] += a0.y * w.w;
      acc[2][0] += a0.z * w.x; acc[2][1] += a0.z * w.y; acc[2][2] += a0.z * w.z; acc[2][3] += a0.z * w.w;
      acc[3][0] += a0.w * w.x; acc[3][1] += a0.w * w.y; acc[3][2] += a0.w * w.z; acc[3][3] += a0.w * w.w;
      acc[4][0] += a1.x * w.x; acc[4][1] += a1.x * w.y; acc[4][2] += a1.x * w.z; acc[4][3] += a1.x * w.w;
      acc[5][0] += a1.y * w.x; acc[5][1] += a1.y * w.y; acc[5][2] += a1.y * w.z; acc[5][3] += a1.y * w.w;
      acc[6][0] += a1.z * w.x; acc[6][1] += a1.z * w.y; acc[6][2] += a1.z * w.z; acc[6][3] += a1.z * w.w;
      acc[7][0] += a1.w * w.x; acc[7][1] += a1.w * w.y; acc[7][2] += a1.w * w.z; acc[7][3] += a1.w * w.w;
    }
    __syncthreads();
  }

  const float qscale = 0.17677669529663689f;  // 1/sqrt(32)
  float4 bgv = make_float4(0.f, 0.f, 0.f, 0.f);
  if (seg == 3) bgv = *(const float4*)(bg + nw + tx * 4);
#pragma unroll
  for (int i = 0; i < 8; ++i) {
    int row = row0 + ty * 8 + i;
    float4 v = make_float4(acc[i][0], acc[i][1], acc[i][2], acc[i][3]);
    if (seg == 0) {
      v.x *= qscale; v.y *= qscale; v.z *= qscale; v.w *= qscale;
    } else if (seg == 3) {
      v.x = 1.f / (1.f + __expf(-(v.x + bgv.x)));
      v.y = 1.f / (1.f + __expf(-(v.y + bgv.y)));
      v.z = 1.f / (1.f + __expf(-(v.z + bgv.z)));
      v.w = 1.f / (1.f + __expf(-(v.w + bgv.w)));
    }
    *(float4*)(qkvg + (size_t)row * LDQ + n0 + tx * 4) = v;
  }
}

// ---------------- fused masked-softmax attention + gating ----------------
// one block per (h, srow-in-chunk); thread = query; writes g*softmax(qk+b)v
// into the q slot of qkvg. Mask read with runtime-detected element width.
__global__ __launch_bounds__(256) void attn(
    float* __restrict__ qkvg, const float* __restrict__ biasT,
    const void* __restrict__ maskraw, const unsigned int* __restrict__ flagp,
    int srow0)
{
  __shared__ float4 kL[2048];   // 256 keys x 8 float4 = 32 KB
  __shared__ float4 vL[2048];   // 32 KB
  const int tid = threadIdx.x;
  const int h = blockIdx.x;
  const int srow = srow0 + blockIdx.y;
  float* rowbase = qkvg + (size_t)blockIdx.y * (256 * LDQ);

  // ---- mask bits via ballot; park in vL space before staging ----
  const unsigned int fl = *flagp;
  int mv = fl ? ((const int*)maskraw)[srow * 256 + tid]
              : (int)((const unsigned char*)maskraw)[srow * 256 + tid];
  unsigned long long bb = __ballot(mv != 0);
  unsigned int* scratch = (unsigned int*)&vL[0];
  if ((tid & 63) == 0) {
    int w = tid >> 6;
    scratch[w * 2 + 0] = (unsigned int)(bb & 0xFFFFFFFFull);
    scratch[w * 2 + 1] = (unsigned int)(bb >> 32);
  }
  __syncthreads();
  unsigned int mb[8];
#pragma unroll
  for (int j = 0; j < 8; ++j) mb[j] = scratch[j];
  __syncthreads();

  // ---- stage k,v to LDS; q to registers ----
#pragma unroll
  for (int j = 0; j < 8; ++j) {
    int f = tid + j * 256;
    int l = f >> 3, cv = f & 7;
    kL[f] = *(const float4*)(rowbase + (size_t)l * LDQ + 256 + h * CH + cv * 4);
    vL[f] = *(const float4*)(rowbase + (size_t)l * LDQ + 512 + h * CH + cv * 4);
  }
  float4 q4[8];
  const float* qp = rowbase + (size_t)tid * LDQ + h * CH;
#pragma unroll
  for (int cv = 0; cv < 8; ++cv) q4[cv] = *(const float4*)(qp + cv * 4);
  __syncthreads();

  const float* bT = biasT + h * 65536 + tid;
  float m = -1e30f, lsum = 0.f;
  float4 o4[8];
#pragma unroll
  for (int cv = 0; cv < 8; ++cv) o4[cv] = make_float4(0.f, 0.f, 0.f, 0.f);

  for (int g0 = 0; g0 < 256; g0 += 16) {
    unsigned int gbits = (mb[g0 >> 5] >> (g0 & 31)) & 0xFFFFu;
    if (__builtin_amdgcn_readfirstlane((int)(gbits != 0)) == 0) continue;
    float sc[16];
    float gmax = -1e30f;
#pragma unroll
    for (int j = 0; j < 16; ++j) {
      if (__builtin_amdgcn_readfirstlane((int)((gbits >> j) & 1u))) {
        int kk = g0 + j;
        float s = 0.f;
#pragma unroll
        for (int cv = 0; cv < 8; ++cv) {
          float4 kv = kL[kk * 8 + cv];
          s += q4[cv].x * kv.x; s += q4[cv].y * kv.y;
          s += q4[cv].z * kv.z; s += q4[cv].w * kv.w;
        }
        s += bT[kk * 256];
        sc[j] = s;
        gmax = fmaxf(gmax, s);
      } else {
        sc[j] = -1e30f;
      }
    }
    float mnew = fmaxf(m, gmax);
    float alpha = __expf(m - mnew);
    lsum *= alpha;
#pragma unroll
    for (int cv = 0; cv < 8; ++cv) {
      o4[cv].x *= alpha; o4[cv].y *= alpha; o4[cv].z *= alpha; o4[cv].w *= alpha;
    }
#pragma unroll
    for (int j = 0; j < 16; ++j) {
      if (__builtin_amdgcn_readfirstlane((int)((gbits >> j) & 1u))) {
        int kk = g0 + j;
        float w = __expf(sc[j] - mnew);
        lsum += w;
#pragma unroll
        for (int cv = 0; cv < 8; ++cv) {
          float4 vv = vL[kk * 8 + cv];
          o4[cv].x += w * vv.x; o4[cv].y += w * vv.y;
          o4[cv].z += w * vv.z; o4[cv].w += w * vv.w;
        }
      }
    }
    m = mnew;
  }

  float inv = 1.0f / lsum;
  const float* gp = rowbase + (size_t)tid * LDQ + 768 + h * CH;
  float* op = rowbase + (size_t)tid * LDQ + h * CH;   // gated output -> q slot
#pragma unroll
  for (int cv = 0; cv < 8; ++cv) {
    float4 g = *(const float4*)(gp + cv * 4);
    float4 o = o4[cv];
    o.x *= inv * g.x; o.y *= inv * g.y; o.z *= inv * g.z; o.w *= inv * g.w;
    *(float4*)(op + cv * 4) = o;
  }
}

// ---------------- output projection: out = oG @ Wo + bo (per chunk) ----------------
__global__ __launch_bounds__(256) void out_proj(
    const float* __restrict__ og, const float* __restrict__ Wo,
    const float* __restrict__ bo, float* __restrict__ out)
{
  __shared__ float At[64][132];
  __shared__ float Wl[64][68];
  const int tid = threadIdx.x;
  const int tx = tid & 15, ty = tid >> 4;
  const int n0 = blockIdx.x * 64;
  const int row0 = blockIdx.y * 128;

  float acc[8][4];
#pragma unroll
  for (int i = 0; i < 8; ++i)
#pragma unroll
    for (int j = 0; j < 4; ++j) acc[i][j] = 0.f;

  for (int k0 = 0; k0 < 256; k0 += 64) {
#pragma unroll
    for (int j = 0; j < 8; ++j) {
      int f = tid + j * 256;
      int r = f >> 4, kv = f & 15;
      const float4 a = *(const float4*)(og + (size_t)(row0 + r) * LDQ + k0 + kv * 4);
      At[kv * 4 + 0][r] = a.x; At[kv * 4 + 1][r] = a.y;
      At[kv * 4 + 2][r] = a.z; At[kv * 4 + 3][r] = a.w;
    }
#pragma unroll
    for (int j = 0; j < 4; ++j) {
      int f = tid + j * 256;
      int kr = f >> 4, nv = f & 15;
      *(float4*)&Wl[kr][nv * 4] = *(const float4*)(Wo + (k0 + kr) * 128 + n0 + nv * 4);
    }
    __syncthreads();
#pragma unroll 16
    for (int k = 0; k < 64; ++k) {
      float4 a0 = *(const float4*)&At[k][ty * 8];
      float4 a1 = *(const float4*)&At[k][ty * 8 + 4];
      float4 w  = *(const float4*)&Wl[k][tx * 4];
      acc[0][0] += a0.x * w.x; acc[0][1] += a0.x * w.y; acc[0][2] += a0.x * w.z; acc[0][3] += a0.x * w.w;
      acc[1][0] += a0.y * w.x; acc[1][1] += a0.y * w.y; acc[1][2] += a0.y * w.z; acc[1][3] += a0.y * w.w;
      acc[2][0] += a0.z * w.x; acc[2][1] += a0.z * w.y; acc[2][2] += a0.z * w.z; acc[2][3] += a0.z * w.w;
      acc[3][0] += a0.w * w.x; acc[3][1] += a0.w * w.y; acc[3][2] += a0.w * w.z; acc[3][3] += a0.w * w.w;
      acc[4][0] += a1.x * w.x; acc[4][1] += a1.x * w.y; acc[4][2] += a1.x * w.z; acc[4][3] += a1.x * w.w;
      acc[5][0] += a1.y * w.x; acc[5][1] += a1.y * w.y; acc[5][2] += a1.y * w.z; acc[5][3] += a1.y * w.w;
      acc[6][0] += a1.z * w.x; acc[6][1] += a1.z * w.y; acc[6][2] += a1.z * w.z; acc[6][3] += a1.z * w.w;
      acc[7][0] += a1.w * w.x; acc[7][1] += a1.w * w.y; acc[7][2] += a1.w * w.z; acc[7][3] += a1.w * w.w;
    }
    __syncthreads();
  }

  float4 bv = *(const float4*)(bo + n0 + tx * 4);
#pragma unroll
  for (int i = 0; i < 8; ++i) {
    int row = row0 + ty * 8 + i;
    float4 v = make_float4(acc[i][0] + bv.x, acc[i][1] + bv.y,
                           acc[i][2] + bv.z, acc[i][3] + bv.w);
    *(float4*)(out + (size_t)row * CIN + n0 + tx * 4) = v;
  }
}

extern "C" void kernel_launch(void* const* d_in, const int* in_sizes, int n_in,
                              void* d_out, int out_size, void* d_ws, size_t ws_size,
                              hipStream_t stream) {
  const float* x    = (const float*)d_in[0];
  const float* bias = (const float*)d_in[1];
  const void*  mask = d_in[2];
  const float* Wq   = (const float*)d_in[3];
  const float* Wk   = (const float*)d_in[4];
  const float* Wv   = (const float*)d_in[5];
  const float* Wo   = (const float*)d_in[6];
  const float* bo   = (const float*)d_in[7];
  const float* Wg   = (const float*)d_in[8];
  const float* bg   = (const float*)d_in[9];
  float* out = (float*)d_out;

  // ws layout: [flag 256 B][biasT 2 MiB][qkvg chunk R MiB]
  unsigned int* flag = (unsigned int*)d_ws;
  float* biasT = (float*)((char*)d_ws + 256);
  float* qkvg  = (float*)((char*)d_ws + 256 + (size_t)NH * 65536 * 4);
  const size_t fixed = 256 + (size_t)NH * 65536 * 4;
  const size_t perrow = (size_t)256 * LDQ * 4;   // 1 MiB per srow
  size_t avail = ws_size > fixed ? ws_size - fixed : 0;
  int R = 256;                                    // srows per chunk
  while (R > 1 && (size_t)R * perrow > avail) R >>= 1;

  detect_mask<<<1, 256, 0, stream>>>((const unsigned char*)mask, flag);
  bias_transpose<<<dim3(8, 8, 8), 256, 0, stream>>>(bias, biasT);

  for (int c = 0; c < 256 / R; ++c) {
    const int srow0 = c * R;
    proj_qkvg<<<dim3(16, 2 * R), 256, 0, stream>>>(
        x + (size_t)srow0 * 256 * CIN, Wq, Wk, Wv, Wg, bg, qkvg);
    attn<<<dim3(NH, R), 256, 0, stream>>>(qkvg, biasT, mask, flag, srow0);
    out_proj<<<dim3(2, 2 * R), 256, 0, stream>>>(
        qkvg, Wo, bo, out + (size_t)srow0 * 256 * CIN);
  }
}